// Round 1
// baseline (107.213 us; speedup 1.0000x reference)
//
#include <hip/hip_runtime.h>
#include <hip/hip_fp16.h>
#include <cstdint>
#include <cstddef>

// Problem constants (from reference)
#define B_SZ   512
#define DIN    256
#define DOUT   256
#define KNOTS  64
#define NK     63          // intervals = KNOTS-1
#define HSTEP  (4.0f / 63.0f)

// Per-interval record: {y0, h*m0, y1, h*m1} packed as 4 halfs = 8 bytes.
// One dwordx2 load per (b,i,o) term instead of two dword loads.
struct Half4 { __half2 a, b; };   // a = {y0, h*m0}, b = {y1, h*m1}

// ---- PCHIP slope helpers (match reference semantics exactly, f32) ----
static __device__ __forceinline__ float pchip_edge(float dA, float dB) {
    // m = (3*dA - dB)/2; zero if m*dA <= 0; clamp to 3*dA if sign flip & too big
    float m = 0.5f * (3.0f * dA - dB);
    if (m * dA <= 0.0f) {
        m = 0.0f;
    } else if (dA * dB < 0.0f && fabsf(m) > 3.0f * fabsf(dA)) {
        m = 3.0f * dA;
    }
    return m;
}

static __device__ __forceinline__ float pchip_inner(float d0, float d1) {
    if (d0 * d1 > 0.0f) {
        float denom = d0 + d1;
        if (fabsf(denom) < 1e-12f) return 0.0f;
        return 2.0f * d0 * d1 / denom;
    }
    return 0.0f;
}

// ---- Kernel 1: build per-interval coefficient table ----
// C[(i*NK + k)*DOUT + o] = {y[i,o,k], h*m[i,o,k], y[i,o,k+1], h*m[i,o,k+1]}
// 33 MB total. One block per input dim i, one thread per output dim o.
// Stores are coalesced per k (64 lanes x 8 B contiguous).
__global__ __launch_bounds__(256) void build_coef(const float* __restrict__ y,
                                                  Half4* __restrict__ C) {
    const int i = blockIdx.x;
    const int o = threadIdx.x;
    const float h = HSTEP;

    const float4* r4 = (const float4*)(y + ((size_t)i * DOUT + o) * KNOTS);
    float yv[KNOTS];
#pragma unroll
    for (int q = 0; q < KNOTS / 4; ++q) {
        float4 v = r4[q];
        yv[4 * q + 0] = v.x; yv[4 * q + 1] = v.y;
        yv[4 * q + 2] = v.z; yv[4 * q + 3] = v.w;
    }
    float d[NK];
#pragma unroll
    for (int k = 0; k < NK; ++k) d[k] = (yv[k + 1] - yv[k]) / h;

    Half4* outp = C + (size_t)i * NK * DOUT + o;

    // Rolling slope: mk = slope at knot k, mk1 = slope at knot k+1.
    float mk = pchip_edge(d[0], d[1]);
#pragma unroll
    for (int k = 0; k < NK; ++k) {
        float mk1 = (k < NK - 1) ? pchip_inner(d[k], d[k + 1])
                                 : pchip_edge(d[NK - 1], d[NK - 2]);
        Half4 c;
        c.a = __floats2half2_rn(yv[k],     h * mk);
        c.b = __floats2half2_rn(yv[k + 1], h * mk1);
        outp[(size_t)k * DOUT] = c;
        mk = mk1;
    }
}

// ---- Kernel 2: forward pass ----
// One block per sample b, 1024 threads = 4 quarters x 256 output dims.
// Quarter q accumulates input dims [q*64, q*64+64); LDS reduce at the end.
// 8192 waves total -> 4-8 waves/SIMD (was 2) to hide L3 latency on the
// scattered table-row reads.
__global__ __launch_bounds__(1024) void kan_forward(const float* __restrict__ x,
                                                    const Half4* __restrict__ C,
                                                    const float* __restrict__ bias,
                                                    float* __restrict__ out) {
    __shared__ int   soff[DIN];
    __shared__ float su[DIN];
    __shared__ float part[1024];

    const int b   = blockIdx.x;
    const int tid = threadIdx.x;
    const int o   = tid & (DOUT - 1);
    const int q   = tid >> 8;

    if (tid < DIN) {
        float xv = x[b * DIN + tid];
        float xc = fminf(fmaxf(xv, -2.0f), 2.0f);
        float t  = (xc + 2.0f) / HSTEP;
        int k = (int)floorf(t);
        k = k < 0 ? 0 : (k > NK - 1 ? NK - 1 : k);
        soff[tid] = (tid * NK + k) * DOUT;   // Half4-element offset of interval row
        su[tid]   = t - (float)k;
    }
    __syncthreads();

    float acc = 0.0f;
    const int i0 = q * (DIN / 4);
#pragma unroll 8
    for (int ii = 0; ii < DIN / 4; ++ii) {
        const int i   = i0 + ii;
        const int off = soff[i] + o;
        Half4 v  = C[off];                   // single 8 B load per term
        float u  = su[i];
        float2 p0 = __half22float2(v.a);     // {y0, h*m0}
        float2 p1 = __half22float2(v.b);     // {y1, h*m1}
        float y0 = p0.x, hm0 = p0.y;
        float y1 = p1.x, hm1 = p1.y;
        float dy = y1 - y0;
        float a2 = 3.0f * dy - 2.0f * hm0 - hm1;   // u^2 coeff
        float a3 = hm0 + hm1 - 2.0f * dy;          // u^3 coeff
        acc += fmaf(u, fmaf(u, fmaf(u, a3, a2), hm0), y0);
    }
    part[tid] = acc;
    __syncthreads();

    if (tid < DOUT) {
        float r = part[tid] + part[tid + 256] + part[tid + 512] + part[tid + 768];
        out[b * DOUT + tid] = r + bias[tid];
    }
}

// ---- Fallback: no-workspace path (only if ws_size is too small) ----
__global__ __launch_bounds__(256) void kan_naive(const float* __restrict__ x,
                                                 const float* __restrict__ y,
                                                 const float* __restrict__ bias,
                                                 float* __restrict__ out) {
    __shared__ int   sk[DIN];
    __shared__ float su[DIN];

    const int b   = blockIdx.x;
    const int tid = threadIdx.x;
    const float h = HSTEP;

    {
        float xv = x[b * DIN + tid];
        float xc = fminf(fmaxf(xv, -2.0f), 2.0f);
        float t  = (xc + 2.0f) / h;
        int k = (int)floorf(t);
        k = k < 0 ? 0 : (k > NK - 1 ? NK - 1 : k);
        sk[tid] = k;
        su[tid] = t - (float)k;
    }
    __syncthreads();

    const int o = tid;
    float acc = 0.0f;
    for (int i = 0; i < DIN; ++i) {
        int   k = sk[i];
        float u = su[i];
        const float* r = y + ((size_t)i * DOUT + o) * KNOTS;
        float ym1 = r[k > 0 ? k - 1 : 0];
        float y0  = r[k];
        float y1  = r[k + 1];
        float y2  = r[k < NK - 1 ? k + 2 : KNOTS - 1];
        float dm1 = (y0 - ym1) / h;
        float d0  = (y1 - y0) / h;
        float d1  = (y2 - y1) / h;
        float mk  = (k == 0)      ? pchip_edge(d0, d1)  : pchip_inner(dm1, d0);
        float mk1 = (k == NK - 1) ? pchip_edge(d0, dm1) : pchip_inner(d0, d1);
        float hm0 = h * mk, hm1 = h * mk1;
        float dy = y1 - y0;
        float c2 = 3.0f * dy - 2.0f * hm0 - hm1;
        float c3 = hm0 + hm1 - 2.0f * dy;
        acc += fmaf(u, fmaf(u, fmaf(u, c3, c2), hm0), y0);
    }
    out[b * DOUT + o] = acc + bias[o];
}

extern "C" void kernel_launch(void* const* d_in, const int* in_sizes, int n_in,
                              void* d_out, int out_size, void* d_ws, size_t ws_size,
                              hipStream_t stream) {
    const float* x    = (const float*)d_in[0];   // (B, DIN)
    const float* y    = (const float*)d_in[1];   // (DIN, DOUT, KNOTS)
    const float* bias = (const float*)d_in[2];   // (DOUT,)
    float* out        = (float*)d_out;           // (B, DOUT)

    const size_t need = (size_t)DIN * NK * DOUT * sizeof(Half4); // ~33 MB

    if (ws_size >= need) {
        Half4* C = (Half4*)d_ws;
        build_coef<<<dim3(DIN), dim3(256), 0, stream>>>(y, C);
        kan_forward<<<dim3(B_SZ), dim3(1024), 0, stream>>>(x, C, bias, out);
    } else {
        kan_naive<<<dim3(B_SZ), dim3(256), 0, stream>>>(x, y, bias, out);
    }
}

// Round 2
// 102.076 us; speedup vs baseline: 1.0503x; 1.0503x over previous
//
#include <hip/hip_runtime.h>
#include <hip/hip_fp16.h>
#include <cstdint>
#include <cstddef>

// Problem constants (from reference)
#define B_SZ   512
#define DIN    256
#define DOUT   256
#define KNOTS  64
#define NK     63          // intervals = KNOTS-1
#define HSTEP  (4.0f / 63.0f)

// XCD-affine slicing of the input dimension
#define NSLICE 8                  // = number of XCDs
#define ISLICE (DIN / NSLICE)     // 32 input dims per slice -> 4.03 MB table slice (fits 4 MiB L2)
#define SPB    4                  // samples per forward block (4 x 256 threads)

// Per-interval record: {y0, h*m0, y1, h*m1} packed as 4 halfs = 8 bytes.
struct Half4 { __half2 a, b; };   // a = {y0, h*m0}, b = {y1, h*m1}

// ---- PCHIP slope helpers (match reference semantics exactly, f32) ----
static __device__ __forceinline__ float pchip_edge(float dA, float dB) {
    float m = 0.5f * (3.0f * dA - dB);
    if (m * dA <= 0.0f) {
        m = 0.0f;
    } else if (dA * dB < 0.0f && fabsf(m) > 3.0f * fabsf(dA)) {
        m = 3.0f * dA;
    }
    return m;
}

static __device__ __forceinline__ float pchip_inner(float d0, float d1) {
    if (d0 * d1 > 0.0f) {
        float denom = d0 + d1;
        if (fabsf(denom) < 1e-12f) return 0.0f;
        return 2.0f * d0 * d1 / denom;
    }
    return 0.0f;
}

// ---- Kernel 1: build per-interval coefficient table + init out = bias ----
// C[(i*NK + k)*DOUT + o] = {y[i,o,k], h*m[i,o,k], y[i,o,k+1], h*m[i,o,k+1]}
// Also writes out[b][o] = bias[o] so the forward pass can pure-atomicAdd.
__global__ __launch_bounds__(256) void build_coef(const float* __restrict__ y,
                                                  Half4* __restrict__ C,
                                                  const float* __restrict__ bias,
                                                  float* __restrict__ out) {
    const int i = blockIdx.x;
    const int o = threadIdx.x;
    const float h = HSTEP;

    // out = bias init: 131072 floats over 65536 threads -> one float2 each.
    {
        int t2 = i * 256 + o;                 // float2 index into out
        int o0 = (o * 2) & (DOUT - 1);        // (t2*2) % 256 == (tid*2) % 256
        float2 bv;
        bv.x = bias[o0];
        bv.y = bias[o0 + 1];
        ((float2*)out)[t2] = bv;
    }

    const float4* r4 = (const float4*)(y + ((size_t)i * DOUT + o) * KNOTS);
    float yv[KNOTS];
#pragma unroll
    for (int q = 0; q < KNOTS / 4; ++q) {
        float4 v = r4[q];
        yv[4 * q + 0] = v.x; yv[4 * q + 1] = v.y;
        yv[4 * q + 2] = v.z; yv[4 * q + 3] = v.w;
    }
    float d[NK];
#pragma unroll
    for (int k = 0; k < NK; ++k) d[k] = (yv[k + 1] - yv[k]) / h;

    Half4* outp = C + (size_t)i * NK * DOUT + o;

    float mk = pchip_edge(d[0], d[1]);
#pragma unroll
    for (int k = 0; k < NK; ++k) {
        float mk1 = (k < NK - 1) ? pchip_inner(d[k], d[k + 1])
                                 : pchip_edge(d[NK - 1], d[NK - 2]);
        Half4 c;
        c.a = __floats2half2_rn(yv[k],     h * mk);
        c.b = __floats2half2_rn(yv[k + 1], h * mk1);
        outp[(size_t)k * DOUT] = c;
        mk = mk1;
    }
}

// ---- Kernel 2: forward pass, XCD-affine i-slices ----
// grid = (B/SPB) * NSLICE = 1024 blocks, 1024 threads.
// slice = blockIdx % 8 -> pinned to one XCD by round-robin dispatch; that
// XCD's L2 then holds exactly its 4.03 MB table slice, so the 268 MB of
// logical gather reads become L2 hits (34.5 TB/s) instead of L3 (~6 TB/s).
// Each block: 4 samples x 256 outputs x 32 input dims; one atomicAdd per
// (sample, o) merges the 8 slice partials into out (pre-initialized to bias).
__global__ __launch_bounds__(1024) void kan_forward(const float* __restrict__ x,
                                                    const Half4* __restrict__ C,
                                                    float* __restrict__ out) {
    __shared__ int   soff[SPB][ISLICE];
    __shared__ float su[SPB][ISLICE];

    const int bid   = blockIdx.x;
    const int slice = bid & (NSLICE - 1);   // XCD-affine
    const int chunk = bid >> 3;             // sample chunk (0..127)
    const int tid   = threadIdx.x;
    const int s     = tid >> 8;             // sub-block sample 0..3
    const int o     = tid & (DOUT - 1);
    const int i0    = slice * ISLICE;

    if (tid < SPB * ISLICE) {               // 128 threads stage (k,u) for the slice
        const int ss = tid >> 5;
        const int j  = tid & (ISLICE - 1);
        const int b  = chunk * SPB + ss;
        float xv = x[b * DIN + i0 + j];
        float xc = fminf(fmaxf(xv, -2.0f), 2.0f);
        float t  = (xc + 2.0f) / HSTEP;
        int k = (int)floorf(t);
        k = k < 0 ? 0 : (k > NK - 1 ? NK - 1 : k);
        soff[ss][j] = ((i0 + j) * NK + k) * DOUT;   // Half4-element offset
        su[ss][j]   = t - (float)k;
    }
    __syncthreads();

    const int b = chunk * SPB + s;
    float acc = 0.0f;
#pragma unroll 8
    for (int j = 0; j < ISLICE; ++j) {
        const int off = soff[s][j] + o;
        Half4 v  = C[off];                   // single 8 B load per term, L2-resident
        float u  = su[s][j];
        float2 p0 = __half22float2(v.a);     // {y0, h*m0}
        float2 p1 = __half22float2(v.b);     // {y1, h*m1}
        float y0 = p0.x, hm0 = p0.y;
        float y1 = p1.x, hm1 = p1.y;
        float dy = y1 - y0;
        float a2 = 3.0f * dy - 2.0f * hm0 - hm1;   // u^2 coeff
        float a3 = hm0 + hm1 - 2.0f * dy;          // u^3 coeff
        acc += fmaf(u, fmaf(u, fmaf(u, a3, a2), hm0), y0);
    }
    atomicAdd(&out[b * DOUT + o], acc);
}

// ---- Fallback: no-workspace path (only if ws_size is too small) ----
__global__ __launch_bounds__(256) void kan_naive(const float* __restrict__ x,
                                                 const float* __restrict__ y,
                                                 const float* __restrict__ bias,
                                                 float* __restrict__ out) {
    __shared__ int   sk[DIN];
    __shared__ float su[DIN];

    const int b   = blockIdx.x;
    const int tid = threadIdx.x;
    const float h = HSTEP;

    {
        float xv = x[b * DIN + tid];
        float xc = fminf(fmaxf(xv, -2.0f), 2.0f);
        float t  = (xc + 2.0f) / h;
        int k = (int)floorf(t);
        k = k < 0 ? 0 : (k > NK - 1 ? NK - 1 : k);
        sk[tid] = k;
        su[tid] = t - (float)k;
    }
    __syncthreads();

    const int o = tid;
    float acc = 0.0f;
    for (int i = 0; i < DIN; ++i) {
        int   k = sk[i];
        float u = su[i];
        const float* r = y + ((size_t)i * DOUT + o) * KNOTS;
        float ym1 = r[k > 0 ? k - 1 : 0];
        float y0  = r[k];
        float y1  = r[k + 1];
        float y2  = r[k < NK - 1 ? k + 2 : KNOTS - 1];
        float dm1 = (y0 - ym1) / h;
        float d0  = (y1 - y0) / h;
        float d1  = (y2 - y1) / h;
        float mk  = (k == 0)      ? pchip_edge(d0, d1)  : pchip_inner(dm1, d0);
        float mk1 = (k == NK - 1) ? pchip_edge(d0, dm1) : pchip_inner(d0, d1);
        float hm0 = h * mk, hm1 = h * mk1;
        float dy = y1 - y0;
        float c2 = 3.0f * dy - 2.0f * hm0 - hm1;
        float c3 = hm0 + hm1 - 2.0f * dy;
        acc += fmaf(u, fmaf(u, fmaf(u, c3, c2), hm0), y0);
    }
    out[b * DOUT + o] = acc + bias[o];
}

extern "C" void kernel_launch(void* const* d_in, const int* in_sizes, int n_in,
                              void* d_out, int out_size, void* d_ws, size_t ws_size,
                              hipStream_t stream) {
    const float* x    = (const float*)d_in[0];   // (B, DIN)
    const float* y    = (const float*)d_in[1];   // (DIN, DOUT, KNOTS)
    const float* bias = (const float*)d_in[2];   // (DOUT,)
    float* out        = (float*)d_out;           // (B, DOUT)

    const size_t need = (size_t)DIN * NK * DOUT * sizeof(Half4); // ~33 MB

    if (ws_size >= need) {
        Half4* C = (Half4*)d_ws;
        build_coef<<<dim3(DIN), dim3(256), 0, stream>>>(y, C, bias, out);
        kan_forward<<<dim3((B_SZ / SPB) * NSLICE), dim3(1024), 0, stream>>>(x, C, out);
    } else {
        kan_naive<<<dim3(B_SZ), dim3(256), 0, stream>>>(x, y, bias, out);
    }
}